// Round 2
// baseline (108.495 us; speedup 1.0000x reference)
//
#include <hip/hip_runtime.h>
#include <math.h>

namespace {
constexpr int kB  = 16;
constexpr int kNV = 6890;
constexpr int kNF = 13776;
constexpr int kTF = 2 * kNF;      // 27552 triangles per person-pair
constexpr int kP  = kB / 2;       // 8 pairs
constexpr int kC  = 65536;
}
#define SIGMA_F 1e-4f
#define EPS_F   1e-9f
#define THRESH_F 2000.0f
#define WEIGHT_F 0.1f

__global__ void init_sums_kernel(float* __restrict__ sums) {
    int t = threadIdx.x;
    if (t < kP) sums[t] = 0.0f;
}

// One thread per (pair, triangle): write translated vertices (3 x float4) and
// cone data (centroid+radius, unit normal) (2 x float4).
__global__ void build_tris_kernel(const float* __restrict__ verts,
                                  const float* __restrict__ trans,
                                  const int*   __restrict__ faces,
                                  float* __restrict__ tverts,
                                  float* __restrict__ cones) {
    int g = blockIdx.x * blockDim.x + threadIdx.x;
    if (g >= kP * kTF) return;
    int p = g / kTF;
    int t = g - p * kTF;
    int half = (t >= kNF) ? 1 : 0;
    int b = 2 * p + half;
    int f = t - half * kNF;
    float tx = trans[3 * b + 0];
    float ty = trans[3 * b + 1];
    float tz = trans[3 * b + 2];
    float3 v[3];
    float4* vdst = (float4*)(tverts + (size_t)g * 12);
#pragma unroll
    for (int k = 0; k < 3; ++k) {
        int vi = faces[3 * f + k];
        const float* vp = verts + ((size_t)b * kNV + vi) * 3;
        v[k] = make_float3(vp[0] + tx, vp[1] + ty, vp[2] + tz);
        float4 o; o.x = v[k].x; o.y = v[k].y; o.z = v[k].z; o.w = 0.0f;
        vdst[k] = o;
    }
    // receiver frame (match reference order of ops)
    float e1x = v[1].x - v[0].x, e1y = v[1].y - v[0].y, e1z = v[1].z - v[0].z;
    float e2x = v[2].x - v[0].x, e2y = v[2].y - v[0].y, e2z = v[2].z - v[0].z;
    float nx = e1y * e2z - e1z * e2y;
    float ny = e1z * e2x - e1x * e2z;
    float nz = e1x * e2y - e1y * e2x;
    float nn = sqrtf(nx * nx + ny * ny + nz * nz) + EPS_F;
    nx /= nn; ny /= nn; nz /= nn;
    float cx = (v[0].x + v[1].x + v[2].x) / 3.0f;
    float cy = (v[0].y + v[1].y + v[2].y) / 3.0f;
    float cz = (v[0].z + v[1].z + v[2].z) / 3.0f;
    float r2 = 0.0f;
#pragma unroll
    for (int k = 0; k < 3; ++k) {
        float dx = v[k].x - cx, dy = v[k].y - cy, dz = v[k].z - cz;
        r2 = fmaxf(r2, dx * dx + dy * dy + dz * dz);
    }
    float radius = sqrtf(r2);
    float4* cdst = (float4*)(cones + (size_t)g * 8);
    float4 c0; c0.x = cx; c0.y = cy; c0.z = cz; c0.w = radius;
    float4 c1; c1.x = nx; c1.y = ny; c1.z = nz; c1.w = 0.0f;
    cdst[0] = c0;
    cdst[1] = c1;
}

// Main kernel: 1 thread per collision. Flat grid; pair = blockIdx.x % 8 so all
// blocks of a pair land on the same XCD (round-robin dispatch) -> that pair's
// ~2.4 MB of cone+vertex data stays L2-resident (4 MB/XCD).
__global__ void __launch_bounds__(256)
pen_kernel(const int* __restrict__ coll,
           const float* __restrict__ tverts,
           const float* __restrict__ cones,
           float* __restrict__ sums) {
    int blk = blockIdx.x;
    int p = blk & 7;            // XCD-aware: same pair -> same XCD
    int chunk = blk >> 3;
    int i = chunk * blockDim.x + threadIdx.x;
    float local = 0.0f;
    if (i < kC) {
        int2 idx = ((const int2*)coll)[(size_t)p * kC + i];
        if (idx.x != idx.y) {
            const float4* cb = (const float4*)cones + (size_t)p * kTF * 2;
            const float4* vb = (const float4*)tverts + (size_t)p * kTF * 3;
            float4 c0 = cb[(size_t)idx.y * 2 + 0];   // centroid.xyz, radius
            float4 c1 = cb[(size_t)idx.y * 2 + 1];   // unit normal.xyz
            float4 i0 = vb[(size_t)idx.x * 3 + 0];
            float4 i1 = vb[(size_t)idx.x * 3 + 1];
            float4 i2 = vb[(size_t)idx.x * 3 + 2];
            float inv_rad = c0.w + EPS_F;
            float acc = 0.0f;
            float4 iv[3] = {i0, i1, i2};
#pragma unroll
            for (int k = 0; k < 3; ++k) {
                float dx = iv[k].x - c0.x, dy = iv[k].y - c0.y, dz = iv[k].z - c0.z;
                float d = dx * c1.x + dy * c1.y + dz * c1.z;
                float px = dx - d * c1.x, py = dy - d * c1.y, pz = dz - d * c1.z;
                float radial = sqrtf(px * px + py * py + pz * pz);
                float fa = fmaxf(-d / SIGMA_F, 0.0f);
                float fb = fmaxf(1.0f - radial / inv_rad, 0.0f);
                float fd = fa * fb;
                acc += fd * fd;
            }
            local = acc;
        }
    }
    // wave(64) reduce, then block reduce, then 1 atomic per block
#pragma unroll
    for (int off = 32; off > 0; off >>= 1)
        local += __shfl_down(local, off, 64);
    __shared__ float red[4];
    int lane = threadIdx.x & 63;
    int wid  = threadIdx.x >> 6;
    if (lane == 0) red[wid] = local;
    __syncthreads();
    if (threadIdx.x == 0) {
        float s = red[0] + red[1] + red[2] + red[3];
        atomicAdd(&sums[p], s);
    }
}

// Fallback path (ws too small): gather vertices directly.
__device__ __forceinline__ void load_tri_direct(const float* __restrict__ verts,
                                                const float* __restrict__ trans,
                                                const int* __restrict__ faces,
                                                int p, int t, float3 v[3]) {
    int half = (t >= kNF) ? 1 : 0;
    int b = 2 * p + half;
    int f = t - half * kNF;
    float tx = trans[3 * b + 0];
    float ty = trans[3 * b + 1];
    float tz = trans[3 * b + 2];
#pragma unroll
    for (int k = 0; k < 3; ++k) {
        int vi = faces[3 * f + k];
        const float* vp = verts + ((size_t)b * kNV + vi) * 3;
        v[k] = make_float3(vp[0] + tx, vp[1] + ty, vp[2] + tz);
    }
}

__global__ void __launch_bounds__(256)
pen_kernel_direct(const int* __restrict__ coll,
                  const float* __restrict__ verts,
                  const float* __restrict__ trans,
                  const int* __restrict__ faces,
                  float* __restrict__ sums) {
    int p = blockIdx.y;
    int i = blockIdx.x * blockDim.x + threadIdx.x;
    float local = 0.0f;
    if (i < kC) {
        int2 idx = ((const int2*)coll)[(size_t)p * kC + i];
        if (idx.x != idx.y) {
            float3 rv[3], iv[3];
            load_tri_direct(verts, trans, faces, p, idx.y, rv);
            load_tri_direct(verts, trans, faces, p, idx.x, iv);
            float e1x = rv[1].x - rv[0].x, e1y = rv[1].y - rv[0].y, e1z = rv[1].z - rv[0].z;
            float e2x = rv[2].x - rv[0].x, e2y = rv[2].y - rv[0].y, e2z = rv[2].z - rv[0].z;
            float nx = e1y * e2z - e1z * e2y;
            float ny = e1z * e2x - e1x * e2z;
            float nz = e1x * e2y - e1y * e2x;
            float nn = sqrtf(nx * nx + ny * ny + nz * nz) + EPS_F;
            nx /= nn; ny /= nn; nz /= nn;
            float cx = (rv[0].x + rv[1].x + rv[2].x) / 3.0f;
            float cy = (rv[0].y + rv[1].y + rv[2].y) / 3.0f;
            float cz = (rv[0].z + rv[1].z + rv[2].z) / 3.0f;
            float r2 = 0.0f;
#pragma unroll
            for (int k = 0; k < 3; ++k) {
                float dx = rv[k].x - cx, dy = rv[k].y - cy, dz = rv[k].z - cz;
                r2 = fmaxf(r2, dx * dx + dy * dy + dz * dz);
            }
            float radius = sqrtf(r2);
            float inv_rad = radius + EPS_F;
            float acc = 0.0f;
#pragma unroll
            for (int k = 0; k < 3; ++k) {
                float dx = iv[k].x - cx, dy = iv[k].y - cy, dz = iv[k].z - cz;
                float d = dx * nx + dy * ny + dz * nz;
                float px = dx - d * nx, py = dy - d * ny, pz = dz - d * nz;
                float radial = sqrtf(px * px + py * py + pz * pz);
                float fa = fmaxf(-d / SIGMA_F, 0.0f);
                float fb = fmaxf(1.0f - radial / inv_rad, 0.0f);
                float fd = fa * fb;
                acc += fd * fd;
            }
            local = acc;
        }
    }
#pragma unroll
    for (int off = 32; off > 0; off >>= 1)
        local += __shfl_down(local, off, 64);
    __shared__ float red[4];
    int lane = threadIdx.x & 63;
    int wid  = threadIdx.x >> 6;
    if (lane == 0) red[wid] = local;
    __syncthreads();
    if (threadIdx.x == 0) {
        float s = red[0] + red[1] + red[2] + red[3];
        atomicAdd(&sums[p], s);
    }
}

__global__ void finalize_kernel(const float* __restrict__ sums, float* __restrict__ out) {
    if (threadIdx.x == 0 && blockIdx.x == 0) {
        float cnt = 0.0f, vals = 0.0f;
#pragma unroll
        for (int p = 0; p < kP; ++p) {
            float pen = sums[p];
            float keep = (pen < THRESH_F) ? 1.0f : 0.0f;
            cnt += keep;
            float s = 1.0f / (1.0f + expf(-pen / THRESH_F));
            vals += (s - 0.5f) * keep;
        }
        float loss = (cnt > 0.0f) ? (vals / fmaxf(cnt, 1.0f)) : 0.0f;
        out[0] = loss * WEIGHT_F;
    }
}

extern "C" void kernel_launch(void* const* d_in, const int* in_sizes, int n_in,
                              void* d_out, int out_size, void* d_ws, size_t ws_size,
                              hipStream_t stream) {
    const float* verts = (const float*)d_in[0];
    const float* trans = (const float*)d_in[1];
    const int*   faces = (const int*)d_in[2];
    const int*   coll  = (const int*)d_in[3];
    float* out  = (float*)d_out;
    float* sums = (float*)d_ws;

    const size_t cones_off = 256;
    const size_t cones_bytes = (size_t)kP * kTF * 8 * sizeof(float);   // 7.05 MB
    const size_t tverts_off = cones_off + cones_bytes;
    const size_t tverts_bytes = (size_t)kP * kTF * 12 * sizeof(float); // 10.6 MB

    init_sums_kernel<<<1, 64, 0, stream>>>(sums);

    if (ws_size >= tverts_off + tverts_bytes) {
        float* cones  = (float*)((char*)d_ws + cones_off);
        float* tverts = (float*)((char*)d_ws + tverts_off);
        int nt = kP * kTF;
        build_tris_kernel<<<(nt + 255) / 256, 256, 0, stream>>>(verts, trans, faces, tverts, cones);
        // flat grid: 8 pairs x 256 chunks = 2048 blocks; pair = blk % 8 (XCD-pinned)
        pen_kernel<<<kP * (kC / 256), 256, 0, stream>>>(coll, tverts, cones, sums);
    } else {
        dim3 grid_main(kC / 256, kP);
        pen_kernel_direct<<<grid_main, 256, 0, stream>>>(coll, verts, trans, faces, sums);
    }
    finalize_kernel<<<1, 64, 0, stream>>>(sums, out);
}